// Round 1
// baseline (2525.313 us; speedup 1.0000x reference)
//
#include <hip/hip_runtime.h>
#include <stdint.h>

#define IN_F   20000
#define OUT_F  3000
#define BATCH  8192

// ---------------------------------------------------------------------------
// Kernel 1: transpose + f32->bf16 downcast.  x [BATCH, IN_F] f32 row-major
// -> xT [IN_F, BATCH] bf16 (raw ushort).  64x64 LDS tile, both phases
// coalesced, tile[64][65] padding kills bank conflicts.
// ---------------------------------------------------------------------------
__global__ __launch_bounds__(256)
void k_transpose(const float* __restrict__ x, uint16_t* __restrict__ xT) {
    __shared__ float tile[64][65];
    const int c0 = blockIdx.x * 64;     // column (IN_F) tile base
    const int b0 = blockIdx.y * 64;     // batch tile base
    const int tid = threadIdx.x;

#pragma unroll
    for (int i = 0; i < 16; ++i) {
        int idx = tid + i * 256;
        int b = idx >> 6, c = idx & 63;      // lanes consecutive in c -> coalesced
        int cc = c0 + c;
        float v = 0.0f;
        if (cc < IN_F) v = x[(size_t)(b0 + b) * IN_F + cc];
        tile[b][c] = v;
    }
    __syncthreads();
#pragma unroll
    for (int i = 0; i < 16; ++i) {
        int idx = tid + i * 256;
        int c = idx >> 6, b = idx & 63;      // lanes consecutive in b -> coalesced
        int cc = c0 + c;
        if (cc < IN_F) {
            uint32_t u = __float_as_uint(tile[b][c]);
            // round-to-nearest-even bf16 (inputs are finite, no NaN path needed)
            uint32_t r = (u + 0x7fffu + ((u >> 16) & 1u)) >> 16;
            xT[(size_t)cc * BATCH + (b0 + b)] = (uint16_t)r;
        }
    }
}

// ---------------------------------------------------------------------------
// Kernel 2: CSR row_ptr[OUT_F+1] from sorted `rows` (row-major coalesced COO).
// Thread k owns boundaries in (rows[k-1], rows[k]] -> disjoint writes.
// ---------------------------------------------------------------------------
__global__ __launch_bounds__(256)
void k_row_ptr(const int* __restrict__ rows, int* __restrict__ row_ptr, int nnz) {
    int k = blockIdx.x * 256 + threadIdx.x;
    if (k >= nnz) return;
    int r  = rows[k];
    int rp = (k == 0) ? -1 : rows[k - 1];
    for (int q = rp + 1; q <= r; ++q) row_ptr[q] = k;
    if (k == nnz - 1) {
        for (int q = r + 1; q <= OUT_F; ++q) row_ptr[q] = nnz;
    }
}

// ---------------------------------------------------------------------------
// Kernel 3: SpMM.  Block = 128 threads = 16 rows x 8 lanes; each lane owns
// 8 consecutive batch elements (one 16B dwordx4 of bf16 per nnz).
// Grid swizzle: blockIdx%8 -> XCD (round-robin dispatch heuristic); each XCD
// walks its own batch tiles so the 2.56 MB xT slice stays in its 4 MB L2
// across the ~30x column reuse.
// ---------------------------------------------------------------------------
#define ROWS_PB 16
#define LANES   8
#define BT      64                                    // batch per block
#define NRG     ((OUT_F + ROWS_PB - 1) / ROWS_PB)     // 188 row groups
#define NTILES  (BATCH / BT)                          // 128 batch tiles
#define TPX     (NTILES / 8)                          // 16 tiles per XCD

__global__ __launch_bounds__(128)
void k_spmm(const uint16_t* __restrict__ xT, const float* __restrict__ w,
            const float* __restrict__ bias, const int* __restrict__ cols,
            const int* __restrict__ row_ptr, float* __restrict__ out) {
    const int i = blockIdx.x;
    const int xcd = i & 7;
    const int j = i >> 3;
    const int tile_local = j / NRG;            // 0..TPX-1, slow per XCD
    const int row_grp   = j - tile_local * NRG; // 0..NRG-1, fast per XCD
    const int tile = xcd + 8 * tile_local;      // 0..127
    const int b0 = tile * BT;

    const int t = threadIdx.x;
    const int row_sub = t >> 3;     // 0..15
    const int lane8  = t & 7;       // 0..7
    const int r = row_grp * ROWS_PB + row_sub;
    if (r >= OUT_F) return;

    const int kbeg = row_ptr[r];
    const int kend = row_ptr[r + 1];

    const uint16_t* xbase = xT + (size_t)(b0 + lane8 * 8);

    float acc0 = 0.f, acc1 = 0.f, acc2 = 0.f, acc3 = 0.f;
    float acc4 = 0.f, acc5 = 0.f, acc6 = 0.f, acc7 = 0.f;

    for (int k = kbeg; k < kend; ++k) {
        int   c  = cols[k];      // 8 lanes/row share address -> broadcast
        float wv = w[k];
        const uint4* p = (const uint4*)(xbase + (size_t)c * BATCH);
        uint4 q = *p;            // 8 bf16, 16B aligned
        float x0 = __uint_as_float(q.x << 16);
        float x1 = __uint_as_float(q.x & 0xffff0000u);
        float x2 = __uint_as_float(q.y << 16);
        float x3 = __uint_as_float(q.y & 0xffff0000u);
        float x4 = __uint_as_float(q.z << 16);
        float x5 = __uint_as_float(q.z & 0xffff0000u);
        float x6 = __uint_as_float(q.w << 16);
        float x7 = __uint_as_float(q.w & 0xffff0000u);
        acc0 = fmaf(wv, x0, acc0);
        acc1 = fmaf(wv, x1, acc1);
        acc2 = fmaf(wv, x2, acc2);
        acc3 = fmaf(wv, x3, acc3);
        acc4 = fmaf(wv, x4, acc4);
        acc5 = fmaf(wv, x5, acc5);
        acc6 = fmaf(wv, x6, acc6);
        acc7 = fmaf(wv, x7, acc7);
    }

    const float bv = bias[r];
    const int   bb = b0 + lane8 * 8;
    float res[8] = {acc0, acc1, acc2, acc3, acc4, acc5, acc6, acc7};
#pragma unroll
    for (int e = 0; e < 8; ++e) {
        out[(size_t)(bb + e) * OUT_F + r] = res[e] + bv;
    }
}

// ---------------------------------------------------------------------------
extern "C" void kernel_launch(void* const* d_in, const int* in_sizes, int n_in,
                              void* d_out, int out_size, void* d_ws, size_t ws_size,
                              hipStream_t stream) {
    const float* x    = (const float*)d_in[0];   // [BATCH, IN_F] f32
    const float* w    = (const float*)d_in[1];   // [NNZ] f32
    const float* bias = (const float*)d_in[2];   // [OUT_F] f32
    const int*   rows = (const int*)d_in[3];     // [NNZ] i32, sorted (row-major)
    const int*   cols = (const int*)d_in[4];     // [NNZ] i32
    float*       out  = (float*)d_out;           // [BATCH, OUT_F] f32
    const int    nnz  = in_sizes[1];

    // workspace layout: [0,16K) row_ptr (3001 ints); [16K, +327.68MB) xT bf16
    int*      row_ptr = (int*)d_ws;
    uint16_t* xT      = (uint16_t*)((char*)d_ws + 16384);

    dim3 gT((IN_F + 63) / 64, BATCH / 64);
    hipLaunchKernelGGL(k_transpose, gT, dim3(256), 0, stream, x, xT);
    hipLaunchKernelGGL(k_row_ptr, dim3((nnz + 255) / 256), dim3(256), 0, stream,
                       rows, row_ptr, nnz);
    hipLaunchKernelGGL(k_spmm, dim3(8 * TPX * NRG), dim3(128), 0, stream,
                       xT, w, bias, cols, row_ptr, out);
}